// Round 4
// baseline (293.021 us; speedup 1.0000x reference)
//
#include <hip/hip_runtime.h>
#include <cstdint>
#include <cstddef>

#define DIM    512
#define HEADS  8
#define DHEAD  64
#define NSEQ   256
#define BATCH  64
#define NROWS  (BATCH * NSEQ)   // 16384
#define HB     (HEADS * BATCH)  // 512

typedef unsigned short u16;
typedef __bf16 bf16x8 __attribute__((ext_vector_type(8)));
typedef float  f32x4  __attribute__((ext_vector_type(4)));

__device__ __forceinline__ float sigmoidf_(float x) { return 1.0f / (1.0f + expf(-x)); }

__device__ __forceinline__ u16 f2bf(float f) {
    union { float f; unsigned u; } a; a.f = f;
    return (u16)((a.u + 0x7fffu + ((a.u >> 16) & 1u)) >> 16);   // RNE
}

__device__ __forceinline__ void gload16(const void* g, void* l) {
    __builtin_amdgcn_global_load_lds((const __attribute__((address_space(1))) void*)g,
                                     (__attribute__((address_space(3))) void*)l, 16, 0, 0);
}

// ---------------------------------------------------------------------------
// Kernel 1: both weight transposes in one launch. z=0: W_in, z=1: W_out.
// ---------------------------------------------------------------------------
__global__ __launch_bounds__(256)
void transpose_cast_kernel(const float* __restrict__ W0, const float* __restrict__ W1,
                           u16* __restrict__ WT)
{
    __shared__ float tile[64][65];
    const int t = threadIdx.x;
    const int bx = blockIdx.x * 64, by = blockIdx.y * 64;
    const float* W = blockIdx.z ? W1 : W0;
    u16* dst = WT + (size_t)blockIdx.z * 512 * 512;
#pragma unroll
    for (int i = 0; i < 16; ++i) {
        int idx = i * 256 + t, r = idx >> 6, c = idx & 63;
        tile[r][c] = W[(size_t)(by + r) * DIM + bx + c];
    }
    __syncthreads();
#pragma unroll
    for (int i = 0; i < 16; ++i) {
        int idx = i * 256 + t, r = idx >> 6, c = idx & 63;
        dst[(size_t)(bx + r) * DIM + by + c] = f2bf(tile[c][r]);
    }
}

// ---------------------------------------------------------------------------
// Kernel 2: fused LN + bf16 MFMA GEMM over batched q|k|v (M = 49152).
//   Prologue: per-row LN stats from fp32 source (16 lanes/row, coalesced).
//   K-loop:   A staged with LN transform + cast; B via global_load_lds.
//   Epilogue: LDS bounce -> coalesced Fseq (q only, seq-major) + FT (dim-major).
// ---------------------------------------------------------------------------
__global__ __launch_bounds__(256)
void fused_in_gemm_kernel(const float* __restrict__ qp, const float* __restrict__ kp,
                          const float* __restrict__ vp, const float* __restrict__ gam,
                          const float* __restrict__ bet, const u16* __restrict__ BT,
                          u16* __restrict__ FT, u16* __restrict__ Fseq)
{
    __shared__ u16 As[128 * 32];
    __shared__ u16 Bs[128 * 32];
    __shared__ u16 Ct[128 * 136];
    __shared__ float2 lnst[128];
    const int t = threadIdx.x, lane = t & 63, w = t >> 6;
    const int wr = w >> 1, wc = w & 1;
    const int r0 = blockIdx.x * 128, c0 = blockIdx.y * 128;
    const int tns = r0 >> 14;
    const float* X = (tns == 0) ? qp : (tns == 1) ? kp : vp;
    const int lr0 = r0 & 16383;
    const int cl = lane & 15, qd = lane >> 4;

    // ---- LN stats: 8 passes x 16 rows, 16 lanes per row ----
    {
        const int rl = t >> 4, l16 = t & 15;
        for (int rg = 0; rg < 8; ++rg) {
            int row = rg * 16 + rl;
            const float* xr = X + (size_t)(lr0 + row) * DIM;
            float s = 0.f, sq = 0.f;
#pragma unroll
            for (int j2 = 0; j2 < 8; ++j2) {
                float4 xv = *(const float4*)(xr + l16 * 4 + j2 * 64);
                s += xv.x + xv.y + xv.z + xv.w;
                sq += xv.x * xv.x + xv.y * xv.y + xv.z * xv.z + xv.w * xv.w;
            }
#pragma unroll
            for (int o = 8; o > 0; o >>= 1) { s += __shfl_xor(s, o, 64); sq += __shfl_xor(sq, o, 64); }
            if (l16 == 0) {
                float mu = s * (1.f / DIM);
                float var = sq * (1.f / DIM) - mu * mu;
                lnst[row] = make_float2(mu, rsqrtf(var + 1e-5f));
            }
        }
    }
    __syncthreads();
    float2 ms[4];
#pragma unroll
    for (int i = 0; i < 4; ++i) ms[i] = lnst[(t >> 3) + 32 * i];
    const int c4 = (t & 7) * 4;

    f32x4 acc[4][4];
#pragma unroll
    for (int i = 0; i < 4; ++i)
#pragma unroll
        for (int j = 0; j < 4; ++j) acc[i][j] = (f32x4){0.f, 0.f, 0.f, 0.f};

    for (int k0 = 0; k0 < DIM; k0 += 32) {
        float4 g4 = *(const float4*)(gam + k0 + c4);
        float4 b4 = *(const float4*)(bet + k0 + c4);
#pragma unroll
        for (int i = 0; i < 2; ++i) {                 // B: 512 16B chunks
            int idx = i * 256 + t, row = idx >> 2, ch = idx & 3;
            gload16(BT + (size_t)(c0 + row) * DIM + k0 + ch * 8, Bs + idx * 8);
        }
#pragma unroll
        for (int i = 0; i < 4; ++i) {                 // A: LN transform + cast
            int row = (t >> 3) + 32 * i;
            float4 xv = *(const float4*)(X + (size_t)(lr0 + row) * DIM + k0 + c4);
            float2 m = ms[i];
            union { u16 h[4]; ushort4 u; } h4;
            h4.h[0] = f2bf((xv.x - m.x) * m.y * g4.x + b4.x);
            h4.h[1] = f2bf((xv.y - m.x) * m.y * g4.y + b4.y);
            h4.h[2] = f2bf((xv.z - m.x) * m.y * g4.z + b4.z);
            h4.h[3] = f2bf((xv.w - m.x) * m.y * g4.w + b4.w);
            *(ushort4*)(As + row * 32 + c4) = h4.u;
        }
        __syncthreads();
        bf16x8 af[4], bfr[4];
#pragma unroll
        for (int mi = 0; mi < 4; ++mi)
            af[mi] = *(const bf16x8*)(As + (wr * 64 + mi * 16 + cl) * 32 + qd * 8);
#pragma unroll
        for (int ni = 0; ni < 4; ++ni)
            bfr[ni] = *(const bf16x8*)(Bs + (wc * 64 + ni * 16 + cl) * 32 + qd * 8);
#pragma unroll
        for (int mi = 0; mi < 4; ++mi)
#pragma unroll
            for (int ni = 0; ni < 4; ++ni)
                acc[mi][ni] = __builtin_amdgcn_mfma_f32_16x16x32_bf16(af[mi], bfr[ni],
                                                                      acc[mi][ni], 0, 0, 0);
        __syncthreads();
    }

    // ---- epilogue ----
    if (tns == 0) {          // seq-major Fseq for attention stage 2 (q only)
#pragma unroll
        for (int mi = 0; mi < 4; ++mi) {
            int lrow = wr * 64 + mi * 16 + qd * 4;
#pragma unroll
            for (int ni = 0; ni < 4; ++ni) {
                int lcol = wc * 64 + ni * 16 + cl;
#pragma unroll
                for (int r = 0; r < 4; ++r)
                    Ct[(lrow + r) * 136 + lcol] = f2bf(acc[mi][ni][r]);
            }
        }
        __syncthreads();
#pragma unroll
        for (int i = 0; i < 8; ++i) {
            int idx = t + 256 * i, row = idx >> 4, ch = idx & 15;
            *(uint4*)(Fseq + (size_t)(lr0 + row) * DIM + c0 + ch * 8) =
                *(const uint4*)(Ct + row * 136 + ch * 8);
        }
        __syncthreads();
    }
    // transposed tile -> dim-major FT, full-line 256B stores per dim row
#pragma unroll
    for (int mi = 0; mi < 4; ++mi) {
        int lrow = wr * 64 + mi * 16 + qd * 4;
#pragma unroll
        for (int ni = 0; ni < 4; ++ni) {
            int lcol = wc * 64 + ni * 16 + cl;
#pragma unroll
            for (int r = 0; r < 4; ++r)
                Ct[lcol * 136 + lrow + r] = f2bf(acc[mi][ni][r]);
        }
    }
    __syncthreads();
    const int b = (r0 >> 8) & 63, n0 = r0 & 255;
#pragma unroll
    for (int i = 0; i < 8; ++i) {
        int idx = t + 256 * i, lc = idx >> 4, ch = idx & 15;
        *(uint4*)(FT + (((size_t)(tns * 64 + b) * 512 + c0 + lc) * 256 + n0 + ch * 8)) =
            *(const uint4*)(Ct + lc * 136 + ch * 8);
    }
}

// ---------------------------------------------------------------------------
// Kernel 3: per-(hb, tns) stats via MFMA Gram (unchanged).
// ---------------------------------------------------------------------------
__global__ __launch_bounds__(256)
void stats_kernel(const u16* __restrict__ FT, float* __restrict__ norms,
                  float2* __restrict__ vc)
{
    __shared__ u16 ET[64 * 264];
    __shared__ float mu[64];
    __shared__ float red[4][64];
    __shared__ float wr3[4][3];
    const int hb = blockIdx.x, tns = blockIdx.y, h = hb >> 6, b = hb & 63;
    const int t = threadIdx.x, lane = t & 63, w = t >> 6, cl = lane & 15, q = lane >> 4;
    const size_t Fb = ((size_t)(tns * 64 + b) * 512 + h * 64) * 256;

#pragma unroll
    for (int i = 0; i < 8; ++i) {
        int idx = t + 256 * i;
        int row = idx >> 5, ch = idx & 31;
        *(bf16x8*)(ET + row * 264 + ch * 8) =
            *(const bf16x8*)(FT + Fb + (size_t)row * 256 + ch * 8);
    }
    __syncthreads();

    {
        float s = 0.f;
#pragma unroll
        for (int d = 0; d < 64; ++d) {
            float x = (float)*(const __bf16*)(ET + d * 264 + t);
            s += x * x;
        }
        norms[((size_t)tns * HB + hb) * 256 + t] = sqrtf(s);
    }
    {
        int d = t & 63, part = t >> 6;
        float s = 0.f;
#pragma unroll
        for (int i = 0; i < 8; ++i) {
            bf16x8 v8 = *(const bf16x8*)(ET + d * 264 + part * 64 + i * 8);
#pragma unroll
            for (int j = 0; j < 8; ++j) s += (float)v8[j];
        }
        red[part][d] = s;
    }
    __syncthreads();
    if (t < 64) mu[t] = (red[0][t] + red[1][t] + red[2][t] + red[3][t]) * (1.f / 256.f);
    __syncthreads();

    f32x4 g[4];
#pragma unroll
    for (int nj = 0; nj < 4; ++nj) g[nj] = (f32x4){0.f, 0.f, 0.f, 0.f};
#pragma unroll
    for (int ks = 0; ks < 8; ++ks) {
        bf16x8 af = *(const bf16x8*)(ET + (16 * w + cl) * 264 + ks * 32 + q * 8);
#pragma unroll
        for (int nj = 0; nj < 4; ++nj) {
            bf16x8 bfr = *(const bf16x8*)(ET + (16 * nj + cl) * 264 + ks * 32 + q * 8);
            g[nj] = __builtin_amdgcn_mfma_f32_16x16x32_bf16(af, bfr, g[nj], 0, 0, 0);
        }
    }
    float t2 = 0.f, d2 = 0.f, vs = 0.f;
#pragma unroll
    for (int nj = 0; nj < 4; ++nj) {
        int j = 16 * nj + cl;
        float mj = mu[j];
#pragma unroll
        for (int r = 0; r < 4; ++r) {
            int i = 16 * w + 4 * q + r;
            float gc = (g[nj][r] - 256.f * mu[i] * mj) * (1.f / 255.f);
            float g2 = gc * gc;
            t2 += g2;
            if (i == j) {
                d2 += g2;
                float sig = sqrtf(gc + 1e-8f);
                vs += fmaxf(1.f - sig, 0.f);
            }
        }
    }
#pragma unroll
    for (int o = 32; o > 0; o >>= 1) {
        t2 += __shfl_xor(t2, o, 64);
        d2 += __shfl_xor(d2, o, 64);
        vs += __shfl_xor(vs, o, 64);
    }
    if (lane == 0) { wr3[w][0] = t2; wr3[w][1] = d2; wr3[w][2] = vs; }
    __syncthreads();
    if (t == 0) {
        float T = 0.f, D = 0.f, V = 0.f;
        for (int i = 0; i < 4; ++i) { T += wr3[i][0]; D += wr3[i][1]; V += wr3[i][2]; }
        vc[(size_t)tns * HB + hb] = make_float2(V * (1.f / 64.f), (T - D) * (1.f / 64.f));
    }
}

// ---------------------------------------------------------------------------
// Kernel 4: attention per (h,b) via MFMA; chunk-combine folded in.
// ---------------------------------------------------------------------------
__global__ __launch_bounds__(256)
void attn_kernel(const u16* __restrict__ FT, const u16* __restrict__ Fseq,
                 const float* __restrict__ norms, const float2* __restrict__ vc,
                 const float* __restrict__ cov_logit, const float* __restrict__ var_logit,
                 u16* __restrict__ G)
{
    __shared__ u16 pool[256 * 72];        // KT[64][136]+VT[64][136] | Os[256][72]
    __shared__ u16 MT[64 * 72];
    __shared__ float invq[256], invk[256], sv[64];
    const int hb = blockIdx.x, h = hb >> 6, b = hb & 63;
    const int t = threadIdx.x, lane = t & 63, w = t >> 6, cl = lane & 15, q = lane >> 4;
    u16* KT = pool;
    u16* VT = pool + 64 * 136;

    // folded combine: s_hb from the 8-chunk sums
    const float cw = sigmoidf_(*cov_logit), vw = sigmoidf_(*var_logit);
    const float cosw = 1.f - cw - vw;
    float s_hb;
    {
        int basec = hb & ~7;
        float vq = 0, cq = 0, vk = 0, ck = 0;
#pragma unroll
        for (int m = 0; m < 8; ++m) {
            float2 a = vc[basec + m];      vq += a.x; cq += a.y;
            float2 bb = vc[HB + basec + m]; vk += bb.x; ck += bb.y;
        }
        s_hb = (cw * cq * ck + vw * vq * vk) * (1.f / 64.f);
    }

    invq[t] = 1.f / norms[((size_t)0 * HB + hb) * 256 + t];
    invk[t] = 1.f / norms[((size_t)1 * HB + hb) * 256 + t];
    __syncthreads();

    const size_t FTk = ((size_t)(1 * 64 + b) * 512 + h * 64) * 256;
    const size_t FTv = ((size_t)(2 * 64 + b) * 512 + h * 64) * 256;
    f32x4 acc1[4];
#pragma unroll
    for (int nj = 0; nj < 4; ++nj) acc1[nj] = (f32x4){0.f, 0.f, 0.f, 0.f};
    float sp[4] = {0.f, 0.f, 0.f, 0.f};

    for (int c = 0; c < 2; ++c) {
#pragma unroll
        for (int i = 0; i < 4; ++i) {
            int idx = t + 256 * i;
            int row = idx >> 4, ch = idx & 15;
            int n0 = c * 128 + ch * 8;
            bf16x8 kv = *(const bf16x8*)(FT + FTk + (size_t)row * 256 + n0);
            bf16x8 vv = *(const bf16x8*)(FT + FTv + (size_t)row * 256 + n0);
            bf16x8 ksc;
#pragma unroll
            for (int j = 0; j < 8; ++j) ksc[j] = (__bf16)((float)kv[j] * invk[n0 + j]);
            *(bf16x8*)(KT + row * 136 + ch * 8) = ksc;
            *(bf16x8*)(VT + row * 136 + ch * 8) = vv;
        }
        __syncthreads();
#pragma unroll
        for (int ks = 0; ks < 4; ++ks) {
            bf16x8 af = *(const bf16x8*)(KT + (16 * w + cl) * 136 + ks * 32 + q * 8);
#pragma unroll
            for (int nj = 0; nj < 4; ++nj) {
                bf16x8 bfr = *(const bf16x8*)(VT + (16 * nj + cl) * 136 + ks * 32 + q * 8);
                if (w == 0) {
                    float s = 0.f;
#pragma unroll
                    for (int j = 0; j < 8; ++j) s += (float)bfr[j];
                    sp[nj] += s;
                }
                acc1[nj] = __builtin_amdgcn_mfma_f32_16x16x32_bf16(af, bfr, acc1[nj], 0, 0, 0);
            }
        }
        __syncthreads();
    }
    if (w == 0) {
#pragma unroll
        for (int nj = 0; nj < 4; ++nj) {
            float s = sp[nj];
            s += __shfl_xor(s, 16, 64);
            s += __shfl_xor(s, 32, 64);
            if (q == 0) sv[16 * nj + cl] = s;
        }
    }
#pragma unroll
    for (int nj = 0; nj < 4; ++nj)
#pragma unroll
        for (int r = 0; r < 4; ++r)
            MT[(16 * nj + cl) * 72 + 16 * w + 4 * q + r] = f2bf(acc1[nj][r]);
    __syncthreads();

    const float s = s_hb;
    f32x4 acc2[4][4];
#pragma unroll
    for (int mi = 0; mi < 4; ++mi)
#pragma unroll
        for (int nj = 0; nj < 4; ++nj) acc2[mi][nj] = (f32x4){0.f, 0.f, 0.f, 0.f};
    const size_t Fq = (size_t)(b * 256) * DIM + h * 64;
#pragma unroll
    for (int ks2 = 0; ks2 < 2; ++ks2) {
        bf16x8 bfm[4];
#pragma unroll
        for (int nj = 0; nj < 4; ++nj)
            bfm[nj] = *(const bf16x8*)(MT + (16 * nj + cl) * 72 + ks2 * 32 + q * 8);
#pragma unroll
        for (int mi = 0; mi < 4; ++mi) {
            bf16x8 aq = *(const bf16x8*)(Fseq + Fq +
                         (size_t)(64 * w + 16 * mi + cl) * DIM + ks2 * 32 + q * 8);
#pragma unroll
            for (int nj = 0; nj < 4; ++nj)
                acc2[mi][nj] = __builtin_amdgcn_mfma_f32_16x16x32_bf16(aq, bfm[nj],
                                                                       acc2[mi][nj], 0, 0, 0);
        }
    }
    __syncthreads();
    u16* Os = pool;
#pragma unroll
    for (int mi = 0; mi < 4; ++mi) {
        int nbase = 64 * w + 16 * mi + 4 * q;
#pragma unroll
        for (int nj = 0; nj < 4; ++nj) {
            int j = 16 * nj + cl;
            float svj = sv[j];
#pragma unroll
            for (int r = 0; r < 4; ++r) {
                float o = cosw * acc2[mi][nj][r] * invq[nbase + r] + s * svj;
                Os[(nbase + r) * 72 + j] = f2bf(o);
            }
        }
    }
    __syncthreads();
#pragma unroll
    for (int i = 0; i < 8; ++i) {
        int cidx = t + 256 * i;
        int row = cidx >> 3, ch = cidx & 7;
        *(uint4*)(G + (size_t)(b * 256 + row) * DIM + h * 64 + ch * 8) =
            *(const uint4*)(Os + row * 72 + ch * 8);
    }
}

// ---------------------------------------------------------------------------
// Kernel 5: out GEMM  out[M,512] = G[M,512] @ W_out^T + b_out (fp32 out)
// ---------------------------------------------------------------------------
__global__ __launch_bounds__(256)
void out_gemm_kernel(const u16* __restrict__ A, const u16* __restrict__ BT,
                     const float* __restrict__ bias, float* __restrict__ C)
{
    __shared__ u16 As[128 * 32];
    __shared__ u16 Bs[128 * 32];
    const int t = threadIdx.x, lane = t & 63, w = t >> 6;
    const int wr = w >> 1, wc = w & 1;
    const int r0 = blockIdx.x * 128, c0 = blockIdx.y * 128;
    const int cl = lane & 15, q = lane >> 4;

    f32x4 acc[4][4];
#pragma unroll
    for (int i = 0; i < 4; ++i)
#pragma unroll
        for (int j = 0; j < 4; ++j) acc[i][j] = (f32x4){0.f, 0.f, 0.f, 0.f};

    for (int k0 = 0; k0 < DIM; k0 += 32) {
#pragma unroll
        for (int i = 0; i < 2; ++i) {
            int idx = i * 256 + t;
            int row = idx >> 2, ch = idx & 3;
            gload16(A  + (size_t)(r0 + row) * DIM + k0 + ch * 8, As + idx * 8);
            gload16(BT + (size_t)(c0 + row) * DIM + k0 + ch * 8, Bs + idx * 8);
        }
        __syncthreads();
        bf16x8 af[4], bfr[4];
#pragma unroll
        for (int mi = 0; mi < 4; ++mi)
            af[mi] = *(const bf16x8*)(As + (wr * 64 + mi * 16 + cl) * 32 + q * 8);
#pragma unroll
        for (int ni = 0; ni < 4; ++ni)
            bfr[ni] = *(const bf16x8*)(Bs + (wc * 64 + ni * 16 + cl) * 32 + q * 8);
#pragma unroll
        for (int mi = 0; mi < 4; ++mi)
#pragma unroll
            for (int ni = 0; ni < 4; ++ni)
                acc[mi][ni] = __builtin_amdgcn_mfma_f32_16x16x32_bf16(af[mi], bfr[ni],
                                                                      acc[mi][ni], 0, 0, 0);
        __syncthreads();
    }
#pragma unroll
    for (int mi = 0; mi < 4; ++mi) {
        int row0 = r0 + wr * 64 + mi * 16 + q * 4;
#pragma unroll
        for (int ni = 0; ni < 4; ++ni) {
            int col = c0 + wc * 64 + ni * 16 + cl;
            float bv = bias[col];
#pragma unroll
            for (int r = 0; r < 4; ++r)
                C[(size_t)(row0 + r) * DIM + col] = acc[mi][ni][r] + bv;
        }
    }
}

// ---------------------------------------------------------------------------
extern "C" void kernel_launch(void* const* d_in, const int* in_sizes, int n_in,
                              void* d_out, int out_size, void* d_ws, size_t ws_size,
                              hipStream_t stream)
{
    const float* q         = (const float*)d_in[0];
    const float* k         = (const float*)d_in[1];
    const float* v         = (const float*)d_in[2];
    const float* ln_g      = (const float*)d_in[3];
    const float* ln_b      = (const float*)d_in[4];
    const float* W_in      = (const float*)d_in[5];
    const float* W_out     = (const float*)d_in[6];
    const float* b_out     = (const float*)d_in[7];
    const float* cov_logit = (const float*)d_in[8];
    const float* var_logit = (const float*)d_in[9];
    float* out = (float*)d_out;

    // workspace (~86 MB):
    char* base = (char*)d_ws;
    u16*    Gb    = (u16*)base;                                   // 16,777,216
    u16*    WT    = (u16*)(base + 16777216);                      //  1,048,576
    u16*    FT    = (u16*)(base + 17825792);                      // 50,331,648
    u16*    Fseq  = (u16*)(base + 68157440);                      // 16,777,216
    float*  norms = (float*)(base + 84934656);                    //  1,048,576
    float2* vc    = (float2*)(base + 85983232);                   //      8,192

    transpose_cast_kernel<<<dim3(8, 8, 2), 256, 0, stream>>>(W_in, W_out, WT);
    fused_in_gemm_kernel<<<dim3(3 * NROWS / 128, 4), 256, 0, stream>>>(
        q, k, v, ln_g, ln_b, WT, FT, Fseq);
    stats_kernel<<<dim3(HB, 2), 256, 0, stream>>>(FT, norms, vc);
    attn_kernel<<<dim3(HB), 256, 0, stream>>>(FT, Fseq, norms, vc,
                                              cov_logit, var_logit, Gb);
    out_gemm_kernel<<<dim3(NROWS / 128, 4), 256, 0, stream>>>(
        Gb, WT + 512 * 512, b_out, out);
}

// Round 5
// 247.151 us; speedup vs baseline: 1.1856x; 1.1856x over previous
//
#include <hip/hip_runtime.h>
#include <cstdint>
#include <cstddef>

#define DIM    512
#define HEADS  8
#define DHEAD  64
#define NSEQ   256
#define BATCH  64
#define NROWS  (BATCH * NSEQ)   // 16384
#define HB     (HEADS * BATCH)  // 512

typedef unsigned short u16;
typedef __bf16 bf16x8 __attribute__((ext_vector_type(8)));
typedef float  f32x4  __attribute__((ext_vector_type(4)));

__device__ __forceinline__ float sigmoidf_(float x) { return 1.0f / (1.0f + expf(-x)); }

__device__ __forceinline__ u16 f2bf(float f) {
    union { float f; unsigned u; } a; a.f = f;
    return (u16)((a.u + 0x7fffu + ((a.u >> 16) & 1u)) >> 16);   // RNE
}

__device__ __forceinline__ void gload16(const void* g, void* l) {
    __builtin_amdgcn_global_load_lds((const __attribute__((address_space(1))) void*)g,
                                     (__attribute__((address_space(3))) void*)l, 16, 0, 0);
}

// ---------------------------------------------------------------------------
// Kernel 1: both weight transposes in one launch. z=0: W_in, z=1: W_out.
// ---------------------------------------------------------------------------
__global__ __launch_bounds__(256)
void transpose_cast_kernel(const float* __restrict__ W0, const float* __restrict__ W1,
                           u16* __restrict__ WT)
{
    __shared__ float tile[64][65];
    const int t = threadIdx.x;
    const int bx = blockIdx.x * 64, by = blockIdx.y * 64;
    const float* W = blockIdx.z ? W1 : W0;
    u16* dst = WT + (size_t)blockIdx.z * 512 * 512;
#pragma unroll
    for (int i = 0; i < 16; ++i) {
        int idx = i * 256 + t, r = idx >> 6, c = idx & 63;
        tile[r][c] = W[(size_t)(by + r) * DIM + bx + c];
    }
    __syncthreads();
#pragma unroll
    for (int i = 0; i < 16; ++i) {
        int idx = i * 256 + t, r = idx >> 6, c = idx & 63;
        dst[(size_t)(bx + r) * DIM + by + c] = f2bf(tile[c][r]);
    }
}

// ---------------------------------------------------------------------------
// Kernel 2: fused LayerNorm + bf16 cast for all of q|k|v in ONE launch.
// One wave per row; rows [0,49152). Output Abf is the GEMM A operand.
// ---------------------------------------------------------------------------
__global__ __launch_bounds__(256)
void ln_cast_kernel(const float* __restrict__ qp, const float* __restrict__ kp,
                    const float* __restrict__ vp, const float* __restrict__ gam,
                    const float* __restrict__ bet, u16* __restrict__ out)
{
    const int wid = threadIdx.x >> 6, lane = threadIdx.x & 63;
    const int row = blockIdx.x * 4 + wid;
    const int tns = row >> 14, lr = row & 16383;
    const float* X = (tns == 0) ? qp : (tns == 1) ? kp : vp;
    const float* xr = X + (size_t)lr * DIM;
    float4 a = *(const float4*)(xr + lane * 8);
    float4 b = *(const float4*)(xr + lane * 8 + 4);
    float v[8] = {a.x, a.y, a.z, a.w, b.x, b.y, b.z, b.w};
    float s = 0.f;
#pragma unroll
    for (int i = 0; i < 8; ++i) s += v[i];
#pragma unroll
    for (int o = 32; o > 0; o >>= 1) s += __shfl_xor(s, o, 64);
    const float mu = s * (1.f / DIM);
    float sq = 0.f;
#pragma unroll
    for (int i = 0; i < 8; ++i) { float d = v[i] - mu; sq += d * d; }
#pragma unroll
    for (int o = 32; o > 0; o >>= 1) sq += __shfl_xor(sq, o, 64);
    const float rstd = rsqrtf(sq * (1.f / DIM) + 1e-5f);
    float4 g0 = *(const float4*)(gam + lane * 8), g1 = *(const float4*)(gam + lane * 8 + 4);
    float4 b0 = *(const float4*)(bet + lane * 8), b1 = *(const float4*)(bet + lane * 8 + 4);
    float gv[8] = {g0.x, g0.y, g0.z, g0.w, g1.x, g1.y, g1.z, g1.w};
    float bv[8] = {b0.x, b0.y, b0.z, b0.w, b1.x, b1.y, b1.z, b1.w};
    union { u16 h[8]; uint4 u; } o16;
#pragma unroll
    for (int i = 0; i < 8; ++i) o16.h[i] = f2bf((v[i] - mu) * rstd * gv[i] + bv[i]);
    *(uint4*)(out + (size_t)row * DIM + lane * 8) = o16.u;
}

// ---------------------------------------------------------------------------
// Kernel 3: batched input GEMM (m97 structure), grid = (4 colblk, 384 rowblk)
// so x (fastest) iterates column-blocks of the SAME A row-tile -> L2 reuse.
// Epilogue: LDS bounce (union'd over As/Bs) -> coalesced Fseq (q) + FT stores.
// ---------------------------------------------------------------------------
__global__ __launch_bounds__(256)
void in_gemm_kernel(const u16* __restrict__ A, const u16* __restrict__ BT,
                    u16* __restrict__ FT, u16* __restrict__ Fseq)
{
    __shared__ u16 shm[128 * 136];        // union: {As[4096] | Bs[4096]} / Ct[17408]
    u16* As = shm;
    u16* Bs = shm + 4096;
    u16* Ct = shm;
    const int t = threadIdx.x, lane = t & 63, w = t >> 6;
    const int wr = w >> 1, wc = w & 1;
    const int c0 = blockIdx.x * 128, r0 = blockIdx.y * 128;
    const int cl = lane & 15, q = lane >> 4;

    f32x4 acc[4][4];
#pragma unroll
    for (int i = 0; i < 4; ++i)
#pragma unroll
        for (int j = 0; j < 4; ++j) acc[i][j] = (f32x4){0.f, 0.f, 0.f, 0.f};

    for (int k0 = 0; k0 < DIM; k0 += 32) {
#pragma unroll
        for (int i = 0; i < 2; ++i) {
            int idx = i * 256 + t;
            int row = idx >> 2, ch = idx & 3;
            gload16(A  + (size_t)(r0 + row) * DIM + k0 + ch * 8, As + idx * 8);
            gload16(BT + (size_t)(c0 + row) * DIM + k0 + ch * 8, Bs + idx * 8);
        }
        __syncthreads();
        bf16x8 af[4], bfr[4];
#pragma unroll
        for (int mi = 0; mi < 4; ++mi)
            af[mi] = *(const bf16x8*)(As + (wr * 64 + mi * 16 + cl) * 32 + q * 8);
#pragma unroll
        for (int ni = 0; ni < 4; ++ni)
            bfr[ni] = *(const bf16x8*)(Bs + (wc * 64 + ni * 16 + cl) * 32 + q * 8);
#pragma unroll
        for (int mi = 0; mi < 4; ++mi)
#pragma unroll
            for (int ni = 0; ni < 4; ++ni)
                acc[mi][ni] = __builtin_amdgcn_mfma_f32_16x16x32_bf16(af[mi], bfr[ni],
                                                                      acc[mi][ni], 0, 0, 0);
        __syncthreads();
    }

    const int tns = r0 >> 14, b = (r0 >> 8) & 63, n0 = r0 & 255;
    const int lr0 = r0 & 16383;

    if (tns == 0) {          // seq-major Fseq (q only)
#pragma unroll
        for (int mi = 0; mi < 4; ++mi) {
            int lrow = wr * 64 + mi * 16 + q * 4;
#pragma unroll
            for (int ni = 0; ni < 4; ++ni) {
                int lcol = wc * 64 + ni * 16 + cl;
#pragma unroll
                for (int r = 0; r < 4; ++r)
                    Ct[(lrow + r) * 136 + lcol] = f2bf(acc[mi][ni][r]);
            }
        }
        __syncthreads();
#pragma unroll
        for (int i = 0; i < 8; ++i) {
            int idx = t + 256 * i, row = idx >> 4, ch = idx & 15;
            *(uint4*)(Fseq + (size_t)(lr0 + row) * DIM + c0 + ch * 8) =
                *(const uint4*)(Ct + row * 136 + ch * 8);
        }
        __syncthreads();
    }
    // transposed tile -> dim-major FT (n contiguous, full-line stores)
#pragma unroll
    for (int mi = 0; mi < 4; ++mi) {
        int lrow = wr * 64 + mi * 16 + q * 4;
#pragma unroll
        for (int ni = 0; ni < 4; ++ni) {
            int lcol = wc * 64 + ni * 16 + cl;
#pragma unroll
            for (int r = 0; r < 4; ++r)
                Ct[lcol * 136 + lrow + r] = f2bf(acc[mi][ni][r]);
        }
    }
    __syncthreads();
#pragma unroll
    for (int i = 0; i < 8; ++i) {
        int idx = t + 256 * i, lc = idx >> 4, ch = idx & 15;
        *(uint4*)(FT + (((size_t)(tns * 64 + b) * 512 + c0 + lc) * 256 + n0 + ch * 8)) =
            *(const uint4*)(Ct + lc * 136 + ch * 8);
    }
}

// ---------------------------------------------------------------------------
// Kernel 4: per-(hb, tns) stats via MFMA Gram.
// ---------------------------------------------------------------------------
__global__ __launch_bounds__(256)
void stats_kernel(const u16* __restrict__ FT, float* __restrict__ norms,
                  float2* __restrict__ vc)
{
    __shared__ u16 ET[64 * 264];
    __shared__ float mu[64];
    __shared__ float red[4][64];
    __shared__ float wr3[4][3];
    const int hb = blockIdx.x, tns = blockIdx.y, h = hb >> 6, b = hb & 63;
    const int t = threadIdx.x, lane = t & 63, w = t >> 6, cl = lane & 15, q = lane >> 4;
    const size_t Fb = ((size_t)(tns * 64 + b) * 512 + h * 64) * 256;

#pragma unroll
    for (int i = 0; i < 8; ++i) {
        int idx = t + 256 * i;
        int row = idx >> 5, ch = idx & 31;
        *(bf16x8*)(ET + row * 264 + ch * 8) =
            *(const bf16x8*)(FT + Fb + (size_t)row * 256 + ch * 8);
    }
    __syncthreads();

    {
        float s = 0.f;
#pragma unroll
        for (int d = 0; d < 64; ++d) {
            float x = (float)*(const __bf16*)(ET + d * 264 + t);
            s += x * x;
        }
        norms[((size_t)tns * HB + hb) * 256 + t] = sqrtf(s);
    }
    {
        int d = t & 63, part = t >> 6;
        float s = 0.f;
#pragma unroll
        for (int i = 0; i < 8; ++i) {
            bf16x8 v8 = *(const bf16x8*)(ET + d * 264 + part * 64 + i * 8);
#pragma unroll
            for (int j = 0; j < 8; ++j) s += (float)v8[j];
        }
        red[part][d] = s;
    }
    __syncthreads();
    if (t < 64) mu[t] = (red[0][t] + red[1][t] + red[2][t] + red[3][t]) * (1.f / 256.f);
    __syncthreads();

    f32x4 g[4];
#pragma unroll
    for (int nj = 0; nj < 4; ++nj) g[nj] = (f32x4){0.f, 0.f, 0.f, 0.f};
#pragma unroll
    for (int ks = 0; ks < 8; ++ks) {
        bf16x8 af = *(const bf16x8*)(ET + (16 * w + cl) * 264 + ks * 32 + q * 8);
#pragma unroll
        for (int nj = 0; nj < 4; ++nj) {
            bf16x8 bfr = *(const bf16x8*)(ET + (16 * nj + cl) * 264 + ks * 32 + q * 8);
            g[nj] = __builtin_amdgcn_mfma_f32_16x16x32_bf16(af, bfr, g[nj], 0, 0, 0);
        }
    }
    float t2 = 0.f, d2 = 0.f, vs = 0.f;
#pragma unroll
    for (int nj = 0; nj < 4; ++nj) {
        int j = 16 * nj + cl;
        float mj = mu[j];
#pragma unroll
        for (int r = 0; r < 4; ++r) {
            int i = 16 * w + 4 * q + r;
            float gc = (g[nj][r] - 256.f * mu[i] * mj) * (1.f / 255.f);
            float g2 = gc * gc;
            t2 += g2;
            if (i == j) {
                d2 += g2;
                float sig = sqrtf(gc + 1e-8f);
                vs += fmaxf(1.f - sig, 0.f);
            }
        }
    }
#pragma unroll
    for (int o = 32; o > 0; o >>= 1) {
        t2 += __shfl_xor(t2, o, 64);
        d2 += __shfl_xor(d2, o, 64);
        vs += __shfl_xor(vs, o, 64);
    }
    if (lane == 0) { wr3[w][0] = t2; wr3[w][1] = d2; wr3[w][2] = vs; }
    __syncthreads();
    if (t == 0) {
        float T = 0.f, D = 0.f, V = 0.f;
        for (int i = 0; i < 4; ++i) { T += wr3[i][0]; D += wr3[i][1]; V += wr3[i][2]; }
        vc[(size_t)tns * HB + hb] = make_float2(V * (1.f / 64.f), (T - D) * (1.f / 64.f));
    }
}

// ---------------------------------------------------------------------------
// Kernel 5: attention per (h,b) via MFMA; chunk-combine folded in.
// ---------------------------------------------------------------------------
__global__ __launch_bounds__(256)
void attn_kernel(const u16* __restrict__ FT, const u16* __restrict__ Fseq,
                 const float* __restrict__ norms, const float2* __restrict__ vc,
                 const float* __restrict__ cov_logit, const float* __restrict__ var_logit,
                 u16* __restrict__ G)
{
    __shared__ u16 pool[256 * 72];
    __shared__ u16 MT[64 * 72];
    __shared__ float invq[256], invk[256], sv[64];
    const int hb = blockIdx.x, h = hb >> 6, b = hb & 63;
    const int t = threadIdx.x, lane = t & 63, w = t >> 6, cl = lane & 15, q = lane >> 4;
    u16* KT = pool;
    u16* VT = pool + 64 * 136;

    const float cw = sigmoidf_(*cov_logit), vw = sigmoidf_(*var_logit);
    const float cosw = 1.f - cw - vw;
    float s_hb;
    {
        int basec = hb & ~7;
        float vq = 0, cq = 0, vk = 0, ck = 0;
#pragma unroll
        for (int m = 0; m < 8; ++m) {
            float2 a = vc[basec + m];       vq += a.x; cq += a.y;
            float2 bb = vc[HB + basec + m]; vk += bb.x; ck += bb.y;
        }
        s_hb = (cw * cq * ck + vw * vq * vk) * (1.f / 64.f);
    }

    invq[t] = 1.f / norms[((size_t)0 * HB + hb) * 256 + t];
    invk[t] = 1.f / norms[((size_t)1 * HB + hb) * 256 + t];
    __syncthreads();

    const size_t FTk = ((size_t)(1 * 64 + b) * 512 + h * 64) * 256;
    const size_t FTv = ((size_t)(2 * 64 + b) * 512 + h * 64) * 256;
    f32x4 acc1[4];
#pragma unroll
    for (int nj = 0; nj < 4; ++nj) acc1[nj] = (f32x4){0.f, 0.f, 0.f, 0.f};
    float sp[4] = {0.f, 0.f, 0.f, 0.f};

    for (int c = 0; c < 2; ++c) {
#pragma unroll
        for (int i = 0; i < 4; ++i) {
            int idx = t + 256 * i;
            int row = idx >> 4, ch = idx & 15;
            int n0 = c * 128 + ch * 8;
            bf16x8 kv = *(const bf16x8*)(FT + FTk + (size_t)row * 256 + n0);
            bf16x8 vv = *(const bf16x8*)(FT + FTv + (size_t)row * 256 + n0);
            bf16x8 ksc;
#pragma unroll
            for (int j = 0; j < 8; ++j) ksc[j] = (__bf16)((float)kv[j] * invk[n0 + j]);
            *(bf16x8*)(KT + row * 136 + ch * 8) = ksc;
            *(bf16x8*)(VT + row * 136 + ch * 8) = vv;
        }
        __syncthreads();
#pragma unroll
        for (int ks = 0; ks < 4; ++ks) {
            bf16x8 af = *(const bf16x8*)(KT + (16 * w + cl) * 136 + ks * 32 + q * 8);
#pragma unroll
            for (int nj = 0; nj < 4; ++nj) {
                bf16x8 bfr = *(const bf16x8*)(VT + (16 * nj + cl) * 136 + ks * 32 + q * 8);
                if (w == 0) {
                    float s = 0.f;
#pragma unroll
                    for (int j = 0; j < 8; ++j) s += (float)bfr[j];
                    sp[nj] += s;
                }
                acc1[nj] = __builtin_amdgcn_mfma_f32_16x16x32_bf16(af, bfr, acc1[nj], 0, 0, 0);
            }
        }
        __syncthreads();
    }
    if (w == 0) {
#pragma unroll
        for (int nj = 0; nj < 4; ++nj) {
            float s = sp[nj];
            s += __shfl_xor(s, 16, 64);
            s += __shfl_xor(s, 32, 64);
            if (q == 0) sv[16 * nj + cl] = s;
        }
    }
#pragma unroll
    for (int nj = 0; nj < 4; ++nj)
#pragma unroll
        for (int r = 0; r < 4; ++r)
            MT[(16 * nj + cl) * 72 + 16 * w + 4 * q + r] = f2bf(acc1[nj][r]);
    __syncthreads();

    f32x4 acc2[4][4];
#pragma unroll
    for (int mi = 0; mi < 4; ++mi)
#pragma unroll
        for (int nj = 0; nj < 4; ++nj) acc2[mi][nj] = (f32x4){0.f, 0.f, 0.f, 0.f};
    const size_t Fq = (size_t)(b * 256) * DIM + h * 64;
#pragma unroll
    for (int ks2 = 0; ks2 < 2; ++ks2) {
        bf16x8 bfm[4];
#pragma unroll
        for (int nj = 0; nj < 4; ++nj)
            bfm[nj] = *(const bf16x8*)(MT + (16 * nj + cl) * 72 + ks2 * 32 + q * 8);
#pragma unroll
        for (int mi = 0; mi < 4; ++mi) {
            bf16x8 aq = *(const bf16x8*)(Fseq + Fq +
                         (size_t)(64 * w + 16 * mi + cl) * DIM + ks2 * 32 + q * 8);
#pragma unroll
            for (int nj = 0; nj < 4; ++nj)
                acc2[mi][nj] = __builtin_amdgcn_mfma_f32_16x16x32_bf16(aq, bfm[nj],
                                                                       acc2[mi][nj], 0, 0, 0);
        }
    }
    __syncthreads();
    u16* Os = pool;
#pragma unroll
    for (int mi = 0; mi < 4; ++mi) {
        int nbase = 64 * w + 16 * mi + 4 * q;
#pragma unroll
        for (int nj = 0; nj < 4; ++nj) {
            int j = 16 * nj + cl;
            float svj = sv[j];
#pragma unroll
            for (int r = 0; r < 4; ++r) {
                float o = cosw * acc2[mi][nj][r] * invq[nbase + r] + s_hb * svj;
                Os[(nbase + r) * 72 + j] = f2bf(o);
            }
        }
    }
    __syncthreads();
#pragma unroll
    for (int i = 0; i < 8; ++i) {
        int cidx = t + 256 * i;
        int row = cidx >> 3, ch = cidx & 7;
        *(uint4*)(G + (size_t)(b * 256 + row) * DIM + h * 64 + ch * 8) =
            *(const uint4*)(Os + row * 72 + ch * 8);
    }
}

// ---------------------------------------------------------------------------
// Kernel 6: out GEMM  out[M,512] = G[M,512] @ W_out^T + b_out (fp32 out)
// ---------------------------------------------------------------------------
__global__ __launch_bounds__(256)
void out_gemm_kernel(const u16* __restrict__ A, const u16* __restrict__ BT,
                     const float* __restrict__ bias, float* __restrict__ C)
{
    __shared__ u16 As[128 * 32];
    __shared__ u16 Bs[128 * 32];
    const int t = threadIdx.x, lane = t & 63, w = t >> 6;
    const int wr = w >> 1, wc = w & 1;
    const int c0 = blockIdx.x * 128, r0 = blockIdx.y * 128;
    const int cl = lane & 15, q = lane >> 4;

    f32x4 acc[4][4];
#pragma unroll
    for (int i = 0; i < 4; ++i)
#pragma unroll
        for (int j = 0; j < 4; ++j) acc[i][j] = (f32x4){0.f, 0.f, 0.f, 0.f};

    for (int k0 = 0; k0 < DIM; k0 += 32) {
#pragma unroll
        for (int i = 0; i < 2; ++i) {
            int idx = i * 256 + t;
            int row = idx >> 2, ch = idx & 3;
            gload16(A  + (size_t)(r0 + row) * DIM + k0 + ch * 8, As + idx * 8);
            gload16(BT + (size_t)(c0 + row) * DIM + k0 + ch * 8, Bs + idx * 8);
        }
        __syncthreads();
        bf16x8 af[4], bfr[4];
#pragma unroll
        for (int mi = 0; mi < 4; ++mi)
            af[mi] = *(const bf16x8*)(As + (wr * 64 + mi * 16 + cl) * 32 + q * 8);
#pragma unroll
        for (int ni = 0; ni < 4; ++ni)
            bfr[ni] = *(const bf16x8*)(Bs + (wc * 64 + ni * 16 + cl) * 32 + q * 8);
#pragma unroll
        for (int mi = 0; mi < 4; ++mi)
#pragma unroll
            for (int ni = 0; ni < 4; ++ni)
                acc[mi][ni] = __builtin_amdgcn_mfma_f32_16x16x32_bf16(af[mi], bfr[ni],
                                                                      acc[mi][ni], 0, 0, 0);
        __syncthreads();
    }
#pragma unroll
    for (int mi = 0; mi < 4; ++mi) {
        int row0 = r0 + wr * 64 + mi * 16 + q * 4;
#pragma unroll
        for (int ni = 0; ni < 4; ++ni) {
            int col = c0 + wc * 64 + ni * 16 + cl;
            float bv = bias[col];
#pragma unroll
            for (int r = 0; r < 4; ++r)
                C[(size_t)(row0 + r) * DIM + col] = acc[mi][ni][r] + bv;
        }
    }
}

// ---------------------------------------------------------------------------
extern "C" void kernel_launch(void* const* d_in, const int* in_sizes, int n_in,
                              void* d_out, int out_size, void* d_ws, size_t ws_size,
                              hipStream_t stream)
{
    const float* q         = (const float*)d_in[0];
    const float* k         = (const float*)d_in[1];
    const float* v         = (const float*)d_in[2];
    const float* ln_g      = (const float*)d_in[3];
    const float* ln_b      = (const float*)d_in[4];
    const float* W_in      = (const float*)d_in[5];
    const float* W_out     = (const float*)d_in[6];
    const float* b_out     = (const float*)d_in[7];
    const float* cov_logit = (const float*)d_in[8];
    const float* var_logit = (const float*)d_in[9];
    float* out = (float*)d_out;

    // workspace (~137 MB):
    char* base = (char*)d_ws;
    u16*    Abf   = (u16*)base;                                   // 50,331,648 (LN'd q|k|v)
    u16*    WT    = (u16*)(base + 50331648);                      //  1,048,576
    u16*    FT    = (u16*)(base + 51380224);                      // 50,331,648
    u16*    Fseq  = (u16*)(base + 101711872);                     // 16,777,216
    float*  norms = (float*)(base + 118489088);                   //  1,048,576
    float2* vc    = (float2*)(base + 119537664);                  //      8,192
    u16*    Gb    = Abf;                                          // alias: Abf dead post-GEMM

    transpose_cast_kernel<<<dim3(8, 8, 2), 256, 0, stream>>>(W_in, W_out, WT);
    ln_cast_kernel<<<dim3(3 * NROWS / 4), 256, 0, stream>>>(q, k, v, ln_g, ln_b, Abf);
    in_gemm_kernel<<<dim3(4, 3 * NROWS / 128), 256, 0, stream>>>(Abf, WT, FT, Fseq);
    stats_kernel<<<dim3(HB, 2), 256, 0, stream>>>(FT, norms, vc);
    attn_kernel<<<dim3(HB), 256, 0, stream>>>(FT, Fseq, norms, vc,
                                              cov_logit, var_logit, Gb);
    out_gemm_kernel<<<dim3(4, NROWS / 128), 256, 0, stream>>>(
        Gb, WT + 512 * 512, b_out, out);
}